// Round 8
// baseline (121.993 us; speedup 1.0000x reference)
//
#include <hip/hip_runtime.h>
#include <cmath>

#define D 128
#define BM 128   // block tile rows
#define BN 64    // block tile cols
#define BK 64    // k-chunk staged in LDS
#define LOG2E 1.4426950408889634

typedef __attribute__((ext_vector_type(8))) _Float16 f16x8;
typedef __attribute__((ext_vector_type(4))) float f32x4;
typedef __attribute__((ext_vector_type(2))) float f32x2;

// async global->LDS 16B copy (global_load_lds_dwordx4); LDS dst is
// lane-contiguous (wave-uniform base + lane*16) -- swizzle lives in gsrc.
__device__ __forceinline__ void async_cp16(const void* g, void* l) {
    __builtin_amdgcn_global_load_lds(
        (__attribute__((address_space(1))) void*)g,
        (__attribute__((address_space(3))) void*)l, 16, 0, 0);
}

// ---------------------------------------------------------------------------
// Prep: fp32 x -> fp16 (RTN) combined [x1; x2], per-row El[r] =
// -gamma*log2e*|row|^2 (log2-domain), AND zero the 64 acc slots (block 0).
// ---------------------------------------------------------------------------
__global__ __launch_bounds__(256) void prep_kernel(
    const float* __restrict__ x1, const float* __restrict__ x2,
    _Float16* __restrict__ xh, float* __restrict__ El,
    double* __restrict__ acc, float gl, int N) {
    int tid = threadIdx.x;
    if (blockIdx.x == 0 && tid < 64) acc[tid] = 0.0;
    int r = blockIdx.x * 16 + (tid >> 4);
    if (r >= 2 * N) return;
    int l = tid & 15;
    const float* row = (r < N) ? x1 + (size_t)r * D : x2 + (size_t)(r - N) * D;
    float4 v0 = ((const float4*)row)[l * 2];
    float4 v1 = ((const float4*)row)[l * 2 + 1];
    float v[8] = {v0.x, v0.y, v0.z, v0.w, v1.x, v1.y, v1.z, v1.w};
    float p = 0.f;
    _Float16 h8[8];
#pragma unroll
    for (int j = 0; j < 8; ++j) {
        p = fmaf(v[j], v[j], p);
        h8[j] = (_Float16)v[j];   // RTN-even
    }
    *(uint4*)(xh + (size_t)r * D + l * 8) = *(uint4*)h8;
#pragma unroll
    for (int off = 8; off; off >>= 1) p += __shfl_down(p, off, 16);
    if (l == 0) El[r] = gl * p;   // gl = -gamma*log2e
}

// ---------------------------------------------------------------------------
// Main: triangular pass over the combined (2N)x(2N) Gram matrix with
// 128(M) x 64(N) tiles. Row bi has 2*bi+2 col-tiles (t0 = bi*(bi+1)).
// Weights fold m11 - 2*m12 + m22 into ONE accumulator:
//   (bj>>1)==bi (inside the diagonal 128-block): +1
//   cross-class ((bi<64) != (bj<128)): -2 ; else: +2
// K in 2 chunks of 64. LDS 24 KiB (A 16K | B 8K), float4-index XOR-swizzled
// by (row&7) -> 0 bank conflicts (measured R2-R7).
// Entry = exp2(c2l*dot + El[i]) * 2^El[j]; plain-vector-C packed epilogue
// (R6 post-mortem: never hand-asm VOP3P).
//
// OCCUPANCY (R7 post-mortem): R7 was latency/barrier-bound at 33% occ;
// binder was regs (C[4][4]=64 AGPR + 60 VGPR = 124 -> 4 waves/EU max).
// Wave tile 64x32 -> C[4][2] = 32 AGPR, ~90 regs total, fits
// launch_bounds(256,5) = 102 regs -> 20 waves/CU, 5 blocks/CU (LDS 120K).
// R4 lesson: if this spills, WRITE_SIZE balloons -- watch it.
// ---------------------------------------------------------------------------
__global__ __launch_bounds__(256, 5) void mmd_mfma_kernel(
    const _Float16* __restrict__ xh, const float* __restrict__ El,
    double* __restrict__ acc, float c2l, int N) {
    __shared__ float4 smem[1536];  // 24 KiB: [0,1024) A, [1024,1536) B

    // triangular decode: row bi starts at f(bi) = bi*(bi+1)
    int t = blockIdx.x;
    int bi = (int)((sqrtf(4.0f * t + 1.0f) - 1.0f) * 0.5f);
    while ((bi + 1) * (bi + 2) <= t) ++bi;
    while (bi * (bi + 1) > t) --bi;
    int bj = t - bi * (bi + 1);        // 0 .. 2*bi+1

    int halfM = N / BM;                // 64: first 64 M-tiles are x1
    int halfN = N / BN;                // 128: first 128 N-tiles are x1
    float w = ((bj >> 1) == bi) ? 1.0f : 2.0f;
    if ((bi < halfM) != (bj < halfN)) w = -2.0f;
    int aBase = bi * BM, bBase = bj * BN;

    int tid = threadIdx.x;
    int lane = tid & 63, wave = tid >> 6;
    int quad = lane >> 4, l16 = lane & 15;
    int wrow = (wave & 1) * 64, wcol = (wave >> 1) * 32;

    f32x4 C[4][2];
#pragma unroll
    for (int i = 0; i < 4; ++i)
#pragma unroll
        for (int j = 0; j < 2; ++j) C[i][j] = {0.f, 0.f, 0.f, 0.f};

    for (int c = 0; c < 2; ++c) {
        if (c) __syncthreads();  // chunk-0 LDS reads done before overwrite
        // stage A: 1024 slots (128 rows x 8 f4), B: 512 slots (64 rows x 8 f4)
#pragma unroll
        for (int i = 0; i < 4; ++i) {
            int slot = i * 256 + tid;
            int row = slot >> 3;
            int kc4 = (slot & 7) ^ (row & 7);
            const void* gp = xh + ((size_t)(aBase + row) * D + c * BK + kc4 * 8);
            async_cp16(gp, &smem[slot]);
        }
#pragma unroll
        for (int i = 0; i < 2; ++i) {
            int slot = i * 256 + tid;
            int row = slot >> 3;
            int kc4 = (slot & 7) ^ (row & 7);
            const void* gp = xh + ((size_t)(bBase + row) * D + c * BK + kc4 * 8);
            async_cp16(gp, &smem[1024 + slot]);
        }
        __syncthreads();
#pragma unroll
        for (int s = 0; s < 2; ++s) {
            int kc4 = s * 4 + quad;
            f16x8 a[4], b[2];
#pragma unroll
            for (int u = 0; u < 4; ++u) {
                int ar = wrow + u * 16 + l16;
                a[u] = *(const f16x8*)&smem[ar * 8 + (kc4 ^ (ar & 7))];
            }
#pragma unroll
            for (int v = 0; v < 2; ++v) {
                int br = wcol + v * 16 + l16;
                b[v] = *(const f16x8*)&smem[1024 + br * 8 + (kc4 ^ (br & 7))];
            }
#pragma unroll
            for (int ti = 0; ti < 4; ++ti)
#pragma unroll
                for (int tj = 0; tj < 2; ++tj)
                    C[ti][tj] = __builtin_amdgcn_mfma_f32_16x16x32_f16(a[ti], b[tj], C[ti][tj], 0, 0, 0);
        }
    }

    // Epilogue. C/D layout (m89-verified): col = lane&15, row = quad*4 + reg.
    int arow0 = aBase + wrow + quad * 4;
    int bcol0 = bBase + wcol + l16;
    float4 ea4[4];
#pragma unroll
    for (int ti = 0; ti < 4; ++ti) ea4[ti] = *(const float4*)&El[arow0 + ti * 16];
    f32x2 cc = {c2l, c2l};
    float lsum = 0.f;
#pragma unroll
    for (int tj = 0; tj < 2; ++tj) {
        float eb = El[bcol0 + tj * 16];
        f32x2 p = {0.f, 0.f};
#pragma unroll
        for (int ti = 0; ti < 4; ++ti) {
            f32x4 d = C[ti][tj];
            f32x2 a01 = cc * f32x2{d.x, d.y} + f32x2{ea4[ti].x, ea4[ti].y};
            f32x2 a23 = cc * f32x2{d.z, d.w} + f32x2{ea4[ti].z, ea4[ti].w};
            f32x2 e;
            e.x = __builtin_amdgcn_exp2f(a01.x);
            e.y = __builtin_amdgcn_exp2f(a01.y);
            f32x2 e2;
            e2.x = __builtin_amdgcn_exp2f(a23.x);
            e2.y = __builtin_amdgcn_exp2f(a23.y);
            p += e + e2;
        }
        lsum = fmaf(p.x + p.y, __builtin_amdgcn_exp2f(eb), lsum);
    }
    double ds = (double)lsum * (double)w;
#pragma unroll
    for (int off = 32; off; off >>= 1) ds += __shfl_down(ds, off);
    __syncthreads();  // LDS frag reads all done; reuse tile buffer as scratch
    double* red = (double*)smem;
    if (lane == 0) red[wave] = ds;
    __syncthreads();
    if (tid == 0)
        atomicAdd(&acc[(bi + bj) & 63], red[0] + red[1] + red[2] + red[3]);
}

// ---------------------------------------------------------------------------
// Finalize: out = sqrt(max(S/N^2, 0)), S already = S11 + S22 - 2*S12.
// ---------------------------------------------------------------------------
__global__ __launch_bounds__(64) void mmd_finalize_kernel(
    const double* __restrict__ acc, float* __restrict__ out, int N) {
    int l = threadIdx.x;
    double v = acc[l];
#pragma unroll
    for (int off = 32; off; off >>= 1) v += __shfl_down(v, off);
    if (l == 0) {
        double nn = (double)N * (double)N;
        double s = v / nn;
        out[0] = (float)sqrt(s > 0.0 ? s : 0.0);
    }
}

extern "C" void kernel_launch(void* const* d_in, const int* in_sizes, int n_in,
                              void* d_out, int out_size, void* d_ws, size_t ws_size,
                              hipStream_t stream) {
    const float* x1 = (const float*)d_in[0];
    const float* x2 = (const float*)d_in[1];
    int N = in_sizes[0] / D;  // 8192

    // ws layout: [0,512) acc (64 doubles); El @8192 (2N f32);
    // xh @73728 (2N*128 fp16 = 4 MB). Total ~4.07 MB.
    double* acc = (double*)d_ws;
    float* El = (float*)((char*)d_ws + 8192);
    _Float16* xh = (_Float16*)((char*)d_ws + 73728);

    double lg = lgamma(0.5 * (D + 1)) - lgamma(0.5 * D);
    double gz = 2.0 * exp(lg);
    double gamma = 1.0 / (2.0 * gz * gz);
    float gl = (float)(-gamma * LOG2E);        // El scale
    float c2l = (float)(2.0 * gamma * LOG2E);  // dot scale (log2 domain)

    prep_kernel<<<(2 * N + 15) / 16, 256, 0, stream>>>(x1, x2, xh, El, acc, gl, N);

    int ntM = 2 * N / BM;                    // 128 M-tile rows
    int nblocks = ntM * (ntM + 1);           // 16512 triangular 128x64 tiles
    mmd_mfma_kernel<<<nblocks, 256, 0, stream>>>(xh, El, acc, c2l, N);

    mmd_finalize_kernel<<<1, 64, 0, stream>>>(acc, (float*)d_out, N);
}

// Round 11
// 107.974 us; speedup vs baseline: 1.1298x; 1.1298x over previous
//
#include <hip/hip_runtime.h>
#include <cmath>

#define D 128
#define BM 128   // block tile (rows and cols)
#define BK 64    // k-chunk staged in LDS
#define LOG2E 1.4426950408889634

typedef __attribute__((ext_vector_type(8))) _Float16 f16x8;
typedef __attribute__((ext_vector_type(4))) float f32x4;
typedef __attribute__((ext_vector_type(2))) float f32x2;

// async global->LDS 16B copy (global_load_lds_dwordx4); LDS dst is
// wave-uniform base + lane*16 -- swizzle lives in gsrc.
// R9/R10 post-mortem: the builtin's immediate `offset` arg does NOT behave
// as a pure global-address offset on gfx950 (identical deterministic absmax
// 3.05e-4 across two MFMA shapes; MUBUF-LDS semantics apply inst_offset to
// the LDS side). ALWAYS pass 0; fold offsets into the pointer.
__device__ __forceinline__ void async_cp16(const void* g, void* l) {
    __builtin_amdgcn_global_load_lds(
        (__attribute__((address_space(1))) void*)g,
        (__attribute__((address_space(3))) void*)l, 16, 0, 0);
}

// ---------------------------------------------------------------------------
// Prep: fp32 x -> fp16 (RTN) combined [x1; x2], per-row El[r] =
// -gamma*log2e*|row|^2 (log2-domain), AND zero the 64 acc slots (block 0).
// ---------------------------------------------------------------------------
__global__ __launch_bounds__(256) void prep_kernel(
    const float* __restrict__ x1, const float* __restrict__ x2,
    _Float16* __restrict__ xh, float* __restrict__ El,
    double* __restrict__ acc, float gl, int N) {
    int tid = threadIdx.x;
    if (blockIdx.x == 0 && tid < 64) acc[tid] = 0.0;
    int r = blockIdx.x * 16 + (tid >> 4);
    if (r >= 2 * N) return;
    int l = tid & 15;
    const float* row = (r < N) ? x1 + (size_t)r * D : x2 + (size_t)(r - N) * D;
    float4 v0 = ((const float4*)row)[l * 2];
    float4 v1 = ((const float4*)row)[l * 2 + 1];
    float v[8] = {v0.x, v0.y, v0.z, v0.w, v1.x, v1.y, v1.z, v1.w};
    float p = 0.f;
    _Float16 h8[8];
#pragma unroll
    for (int j = 0; j < 8; ++j) {
        p = fmaf(v[j], v[j], p);
        h8[j] = (_Float16)v[j];   // RTN-even
    }
    *(uint4*)(xh + (size_t)r * D + l * 8) = *(uint4*)h8;
#pragma unroll
    for (int off = 8; off; off >>= 1) p += __shfl_down(p, off, 16);
    if (l == 0) El[r] = gl * p;   // gl = -gamma*log2e
}

// ---------------------------------------------------------------------------
// Main: one triangular pass over the combined (2N)x(2N) Gram matrix.
// Signed weight folds m11 - 2*m12 + m22 into ONE accumulator:
//   bi==bj: +1; same class off-diag: +2; cross class: -2.
// 128x128 tile (R8: 128x64 regressed -- occupancy was NOT the binder).
// K in 2 chunks of 64. LDS 32 KiB (A|B), float4-granule XOR-swizzle by
// (row&7), 0 bank conflicts (measured R2-R8).
//
// MFMA: v_mfma_f32_16x16x32_f16 -- the m89/m91-HW-verified shape. (R9:
// unverified 32x32 A/B mapping suspected, but R10 proved the 3e-4 bias was
// the global_load_lds immediate offset, not the shape. Staying on the
// verified shape regardless.)
//
// Staging addresses hoisted once; chunk offset applied via POINTER ADD
// (+c*BK elements), builtin immediate always 0 (R9/R10 post-mortem).
//
// REGISTER BUDGET (R4): launch_bounds(256,4)=128 regs fits C[4][4]=64 AGPR
// + ~60 VGPR. (256,5) SPILLS -> 540 MB scratch, 430 us. Tripwire:
// WRITE_SIZE must stay ~KB-scale.
// NO __threadfence (R5: per-block L2 flush, 54 -> 212 us).
// Epilogue in plain vector C (R6: never hand-asm VOP3P).
// ---------------------------------------------------------------------------
__global__ __launch_bounds__(256, 4) void mmd_mfma_kernel(
    const _Float16* __restrict__ xh, const float* __restrict__ El,
    double* __restrict__ acc, float c2l, int N) {
    __shared__ float4 smem[2048];  // 32 KiB: [0,1024) A, [1024,2048) B

    // triangular decode (wave-uniform scalar math)
    int t = blockIdx.x;
    int bi = (int)((sqrtf(8.0f * t + 1.0f) - 1.0f) * 0.5f);
    while ((bi + 1) * (bi + 2) / 2 <= t) ++bi;
    while (bi * (bi + 1) / 2 > t) --bi;
    int bj = t - bi * (bi + 1) / 2;   // bj <= bi

    int half = N / BM;                 // first `half` block-rows are x1
    float w = (bi == bj) ? 1.0f : 2.0f;
    if ((bi < half) != (bj < half)) w = -2.0f;
    int aBase = bi * BM, bBase = bj * BM;

    int tid = threadIdx.x;
    int lane = tid & 63, wave = tid >> 6;
    int quad = lane >> 4, l16 = lane & 15;
    int wrow = (wave & 1) * 64, wcol = (wave >> 1) * 64;

    // hoisted staging addresses (8 slots/thread: 4 A + 4 B)
    const _Float16* gsrc[8];
    float4* ldst[8];
#pragma unroll
    for (int r = 0; r < 2; ++r) {
        int rowBase = r ? bBase : aBase;
#pragma unroll
        for (int i = 0; i < 4; ++i) {
            int slot = i * 256 + tid;            // 0..1023
            int row = slot >> 3;
            int kc4 = (slot & 7) ^ (row & 7);
            gsrc[r * 4 + i] = xh + ((size_t)(rowBase + row) * D + kc4 * 8);
            ldst[r * 4 + i] = &smem[r * 1024 + slot];
        }
    }

    f32x4 C[4][4];
#pragma unroll
    for (int i = 0; i < 4; ++i)
#pragma unroll
        for (int j = 0; j < 4; ++j) C[i][j] = {0.f, 0.f, 0.f, 0.f};

    for (int c = 0; c < 2; ++c) {
        if (c) __syncthreads();  // chunk-0 LDS reads done before overwrite
        int koff = c * BK;       // chunk offset folded into the pointer
#pragma unroll
        for (int q = 0; q < 8; ++q) async_cp16(gsrc[q] + koff, ldst[q]);
        __syncthreads();
#pragma unroll
        for (int s = 0; s < 2; ++s) {
            int kc4 = s * 4 + quad;
            f16x8 a[4], b[4];
#pragma unroll
            for (int u = 0; u < 4; ++u) {
                int ar = wrow + u * 16 + l16;
                a[u] = *(const f16x8*)&smem[ar * 8 + (kc4 ^ (ar & 7))];
                int br = wcol + u * 16 + l16;
                b[u] = *(const f16x8*)&smem[1024 + br * 8 + (kc4 ^ (br & 7))];
            }
#pragma unroll
            for (int ti = 0; ti < 4; ++ti)
#pragma unroll
                for (int tj = 0; tj < 4; ++tj)
                    C[ti][tj] = __builtin_amdgcn_mfma_f32_16x16x32_f16(
                        a[ti], b[tj], C[ti][tj], 0, 0, 0);
        }
    }

    // Epilogue. C/D layout (m89-verified): col = lane&15, row = quad*4 + reg.
    // entry = exp2(c2l*d + ea) * 2^eb, eb factored per column; plain vector C.
    int arow0 = aBase + wrow + quad * 4;
    int bcol0 = bBase + wcol + l16;
    float4 ea4[4];
#pragma unroll
    for (int ti = 0; ti < 4; ++ti) ea4[ti] = *(const float4*)&El[arow0 + ti * 16];
    f32x2 cc = {c2l, c2l};
    float lsum = 0.f;
#pragma unroll
    for (int tj = 0; tj < 4; ++tj) {
        float eb = El[bcol0 + tj * 16];
        f32x2 p = {0.f, 0.f};
#pragma unroll
        for (int ti = 0; ti < 4; ++ti) {
            f32x4 d = C[ti][tj];
            f32x2 a01 = cc * f32x2{d.x, d.y} + f32x2{ea4[ti].x, ea4[ti].y};
            f32x2 a23 = cc * f32x2{d.z, d.w} + f32x2{ea4[ti].z, ea4[ti].w};
            f32x2 e, e2;
            e.x = __builtin_amdgcn_exp2f(a01.x);
            e.y = __builtin_amdgcn_exp2f(a01.y);
            e2.x = __builtin_amdgcn_exp2f(a23.x);
            e2.y = __builtin_amdgcn_exp2f(a23.y);
            p += e + e2;
        }
        lsum = fmaf(p.x + p.y, __builtin_amdgcn_exp2f(eb), lsum);
    }
    double ds = (double)lsum * (double)w;
#pragma unroll
    for (int off = 32; off; off >>= 1) ds += __shfl_down(ds, off);
    __syncthreads();  // LDS frag reads all done; reuse tile buffer as scratch
    double* red = (double*)smem;
    if (lane == 0) red[wave] = ds;
    __syncthreads();
    if (tid == 0)
        atomicAdd(&acc[(bi + bj) & 63], red[0] + red[1] + red[2] + red[3]);
}

// ---------------------------------------------------------------------------
// Finalize: out = sqrt(max(S/N^2, 0)), S already = S11 + S22 - 2*S12.
// ---------------------------------------------------------------------------
__global__ __launch_bounds__(64) void mmd_finalize_kernel(
    const double* __restrict__ acc, float* __restrict__ out, int N) {
    int l = threadIdx.x;
    double v = acc[l];
#pragma unroll
    for (int off = 32; off; off >>= 1) v += __shfl_down(v, off);
    if (l == 0) {
        double nn = (double)N * (double)N;
        double s = v / nn;
        out[0] = (float)sqrt(s > 0.0 ? s : 0.0);
    }
}

extern "C" void kernel_launch(void* const* d_in, const int* in_sizes, int n_in,
                              void* d_out, int out_size, void* d_ws, size_t ws_size,
                              hipStream_t stream) {
    const float* x1 = (const float*)d_in[0];
    const float* x2 = (const float*)d_in[1];
    int N = in_sizes[0] / D;  // 8192

    // ws layout: [0,512) acc (64 doubles); El @8192 (2N f32);
    // xh @73728 (2N*128 fp16 = 4 MB). Total ~4.07 MB.
    double* acc = (double*)d_ws;
    float* El = (float*)((char*)d_ws + 8192);
    _Float16* xh = (_Float16*)((char*)d_ws + 73728);

    double lg = lgamma(0.5 * (D + 1)) - lgamma(0.5 * D);
    double gz = 2.0 * exp(lg);
    double gamma = 1.0 / (2.0 * gz * gz);
    float gl = (float)(-gamma * LOG2E);        // El scale
    float c2l = (float)(2.0 * gamma * LOG2E);  // dot scale (log2 domain)

    prep_kernel<<<(2 * N + 15) / 16, 256, 0, stream>>>(x1, x2, xh, El, acc, gl, N);

    int nt2 = 2 * N / BM;                  // 128 combined block-rows
    int nblocks = nt2 * (nt2 + 1) / 2;     // 8256 triangular blocks
    mmd_mfma_kernel<<<nblocks, 256, 0, stream>>>(xh, El, acc, c2l, N);

    mmd_finalize_kernel<<<1, 64, 0, stream>>>(acc, (float*)d_out, N);
}